// Round 3
// baseline (440.643 us; speedup 1.0000x reference)
//
#include <hip/hip_runtime.h>
#include <stdint.h>

#define S 64
#define NSQ 32
#define Lc 2048
#define Cc 512
#define Ec 128
#define OUT_H (S*NSQ*Lc)   /* 4194304 */

typedef __bf16 bf16x8 __attribute__((ext_vector_type(8)));
typedef float floatx4 __attribute__((ext_vector_type(4)));

__device__ __forceinline__ unsigned short f2bf(float f){
  union { float f; uint32_t u; } v; v.f = f;
  uint32_t r = v.u + 0x7fffu + ((v.u >> 16) & 1u);
  return (unsigned short)(r >> 16);
}

// ---------------------------------------------------------------------------
// k_prep: dynamic weights w[s][c][k], b[s][c]; W1->bf16; W2 rearrange->bf16;
// zero logdet; copy h1 -> out.   grid 512 x 256
// ---------------------------------------------------------------------------
__global__ void k_prep(const float* __restrict__ h, const float* __restrict__ emb,
                       const float* __restrict__ Wa, const float* __restrict__ ba,
                       const float* __restrict__ Wb, const float* __restrict__ bb,
                       const float* __restrict__ W1, const float* __restrict__ W2,
                       float* __restrict__ dynW, float* __restrict__ dynB,
                       unsigned short* __restrict__ W1bf, unsigned short* __restrict__ W2bf,
                       float* __restrict__ out)
{
  __shared__ float embl[Ec];
  int tid = threadIdx.x;
  int b = blockIdx.x;          // 512 blocks, 8 per sample
  int s = b >> 3;
  int o = ((b & 7) << 8) | tid;   // 0..2047 (1536 dynW dots + 512 dynB dots)
  if (tid < Ec) embl[tid] = emb[s*Ec + tid];
  __syncthreads();
  const float* row; float bias; float* dst;
  if (o < 1536) { row = Wa + o*Ec; bias = ba[o]; dst = dynW + s*1536 + o; }
  else { int c = o - 1536; row = Wb + c*Ec; bias = bb[c]; dst = dynB + s*Cc + c; }
  float acc = bias;
  const float4* r4 = (const float4*)row;
  #pragma unroll 8
  for (int e = 0; e < Ec/4; e++) {
    float4 rv = r4[e];
    acc += embl[4*e]*rv.x + embl[4*e+1]*rv.y + embl[4*e+2]*rv.z + embl[4*e+3]*rv.w;
  }
  *dst = acc;

  int gtid = b*256 + tid;      // 0..131071
  // W1 convert: 262144 elems, 2/thread. W1 is [o][c][1] row-major == [o][c].
  {
    float2 wv = ((const float2*)W1)[gtid];
    W1bf[2*gtid]   = f2bf(wv.x);
    W1bf[2*gtid+1] = f2bf(wv.y);
  }
  // W2 rearrange: dst [k][j][c] <- src [j][c][k]  (49152 elems)
  if (gtid < 3*32*Cc) {
    int k = gtid >> 14;
    int rem = gtid & 16383;
    int j = rem >> 9, c = rem & 511;
    W2bf[gtid] = f2bf(W2[j*1536 + c*3 + k]);
  }
  if (gtid < S) out[OUT_H + gtid] = 0.f;   // logdet accumulators
  // h1 copy: first 16 rows of each sample (8192 float4/sample), 4/thread
  {
    const float4* hs = (const float4*)h;
    float4* od = (float4*)out;
    #pragma unroll
    for (int i = 0; i < 4; i++) {
      int v = gtid + i*131072;      // 0..524287
      int ss = v >> 13;             // v / 8192
      int r = v & 8191;
      od[ss*16384 + r] = hs[ss*16384 + r];
    }
  }
}

// ---------------------------------------------------------------------------
// k_fused: per (l-tile, sample) block does:
//   phase A: X2[512 o][128 ll] = relu(W1 @ x + b1), x computed on the fly
//            from h + dynamic depthwise weights; x2 -> LDS (bf16, [130][520])
//   phase B: x3[32 j][128 l] = KW-3 conv(W2, x2) + b2 (MFMA, x2 from LDS)
//   phase C: s=sigmoid+eps, m; out h2' = s*(h2+m); logdet reduce+atomic.
// block 1024 thr (16 waves); grid (17 tiles, 64 samples); lb = t*126,
// x2 cols l_glob = lb-1+ll, valid conv outputs l_loc in [0,126).
// ---------------------------------------------------------------------------
__global__ void __launch_bounds__(1024) k_fused(
    const float* __restrict__ h,
    const unsigned short* __restrict__ W1bf, const float* __restrict__ b1,
    const unsigned short* __restrict__ W2bf, const float* __restrict__ b2,
    const float* __restrict__ dynW, const float* __restrict__ dynB,
    float* __restrict__ out)
{
  extern __shared__ char smem[];
  unsigned short* As  = (unsigned short*)smem;            // [512][72] (phase A)
  unsigned short* Bs  = (unsigned short*)(smem + 73728);  // [128][72] (phase A)
  unsigned short* x2t = (unsigned short*)smem;            // [130][520] (phase B)
  float* x3b = (float*)(smem + 135200);                   // [128][36]
  float* red = (float*)(smem + 153632);                   // [16]

  int tid = threadIdx.x;
  int t = blockIdx.x, s = blockIdx.y;
  int lb = t*126;
  int w = tid >> 6, ln16 = tid & 15, quad = (tid & 63) >> 4;
  int wm = w >> 1, wn = w & 1;          // GEMM wave grid: 8 (o) x 2 (ll)
  int cl = tid & 63, lg = tid >> 6;     // x staging: c-lane, ll-group
  int ll0 = lg*8;

  const float* hbase = h + s*(NSQ*Lc);
  const float* dwp = dynW + s*1536;
  const float* dbp = dynB + s*Cc;

  // -------- phase A: GEMM with pipelined staging --------
  uint4 pw[4];
  float ph[10];
  float w0c, w1c, w2c, bxc;

  #define LOAD_CHUNK(c0_) {                                                  \
    _Pragma("unroll")                                                        \
    for (int j = 0; j < 4; j++) {                                            \
      int u = tid + j*1024;                                                  \
      int row = u >> 3, c16 = u & 7;                                         \
      pw[j] = *(const uint4*)&W1bf[row*512 + (c0_) + c16*8];                 \
    }                                                                        \
    int c_ = (c0_) + cl, q_ = c_ >> 5;                                       \
    const float* hr_ = hbase + q_*Lc;                                        \
    int base_ = lb - 2 + ll0;                                                \
    _Pragma("unroll")                                                        \
    for (int m = 0; m < 10; m++) {                                           \
      int hi_ = base_ + m;                                                   \
      ph[m] = ((unsigned)hi_ < 2048u) ? hr_[hi_] : 0.f;                      \
    }                                                                        \
    w0c = dwp[c_*3 + 0]; w1c = dwp[c_*3 + 1]; w2c = dwp[c_*3 + 2];           \
    bxc = dbp[c_];                                                           \
  }

  floatx4 acc[4][4];
  #pragma unroll
  for (int mi = 0; mi < 4; mi++)
    #pragma unroll
    for (int ni = 0; ni < 4; ni++)
      acc[mi][ni] = (floatx4){0.f,0.f,0.f,0.f};

  LOAD_CHUNK(0);
  for (int ch = 0; ch < 8; ch++) {
    __syncthreads();   // previous chunk's frag reads done; LDS reusable
    #pragma unroll
    for (int j = 0; j < 4; j++) {
      int u = tid + j*1024;
      int row = u >> 3, c16 = u & 7;
      *(uint4*)&As[row*72 + c16*8] = pw[j];
    }
    #pragma unroll
    for (int i = 0; i < 8; i++) {
      float v = fmaxf(w0c*ph[i] + w1c*ph[i+1] + w2c*ph[i+2] + bxc, 0.f);
      Bs[(ll0 + i)*72 + cl] = f2bf(v);
    }
    __syncthreads();
    if (ch < 7) LOAD_CHUNK((ch+1)*64);   // overlap with MFMA below
    #pragma unroll
    for (int kk = 0; kk < 64; kk += 32) {
      bf16x8 af[4], bfr[4];
      #pragma unroll
      for (int mi = 0; mi < 4; mi++)
        af[mi] = *(const bf16x8*)&As[(wm*64 + mi*16 + ln16)*72 + kk + quad*8];
      #pragma unroll
      for (int ni = 0; ni < 4; ni++)
        bfr[ni] = *(const bf16x8*)&Bs[(wn*64 + ni*16 + ln16)*72 + kk + quad*8];
      #pragma unroll
      for (int mi = 0; mi < 4; mi++)
        #pragma unroll
        for (int ni = 0; ni < 4; ni++)
          acc[mi][ni] = __builtin_amdgcn_mfma_f32_16x16x32_bf16(af[mi], bfr[ni], acc[mi][ni], 0, 0, 0);
    }
  }
  __syncthreads();   // all frag reads done before x2t overwrites As/Bs

  // -------- epilogue A: relu+b1 -> x2t (bf16), zero-pad invalid l --------
  #pragma unroll
  for (int mi = 0; mi < 4; mi++) {
    int o = wm*64 + mi*16 + quad*4;
    float4 b1v = *(const float4*)(b1 + o);
    #pragma unroll
    for (int ni = 0; ni < 4; ni++) {
      int ll = wn*64 + ni*16 + ln16;
      int lglob = lb - 1 + ll;
      ushort4 st;
      if ((unsigned)lglob < 2048u) {
        st.x = f2bf(fmaxf(acc[mi][ni][0] + b1v.x, 0.f));
        st.y = f2bf(fmaxf(acc[mi][ni][1] + b1v.y, 0.f));
        st.z = f2bf(fmaxf(acc[mi][ni][2] + b1v.z, 0.f));
        st.w = f2bf(fmaxf(acc[mi][ni][3] + b1v.w, 0.f));
      } else {
        st.x = 0; st.y = 0; st.z = 0; st.w = 0;   // conv2 zero-pad columns
      }
      *(ushort4*)&x2t[ll*520 + o] = st;
    }
  }
  if (tid < 520) ((uint32_t*)&x2t[128*520])[tid] = 0;  // rows 128,129 = 0
  __syncthreads();

  // -------- phase B: KW=3 conv via MFMA; wave = (jh, nt) --------
  {
    int jh = w & 1, nt = w >> 1;
    floatx4 ca = (floatx4){0.f,0.f,0.f,0.f};
    floatx4 cb = (floatx4){0.f,0.f,0.f,0.f};
    #pragma unroll
    for (int k = 0; k < 3; k++) {
      const unsigned short* Wk = W2bf + k*16384 + (jh*16 + ln16)*512;
      const unsigned short* xr = x2t + (nt*16 + ln16 + k)*520;
      #pragma unroll
      for (int c0 = 0; c0 < 512; c0 += 64) {
        bf16x8 a0 = *(const bf16x8*)&Wk[c0 + quad*8];
        bf16x8 v0 = *(const bf16x8*)&xr[c0 + quad*8];
        ca = __builtin_amdgcn_mfma_f32_16x16x32_bf16(a0, v0, ca, 0, 0, 0);
        bf16x8 a1 = *(const bf16x8*)&Wk[c0 + 32 + quad*8];
        bf16x8 v1 = *(const bf16x8*)&xr[c0 + 32 + quad*8];
        cb = __builtin_amdgcn_mfma_f32_16x16x32_bf16(a1, v1, cb, 0, 0, 0);
      }
    }
    float4 b2v = *(const float4*)(b2 + jh*16 + quad*4);
    int l_loc = nt*16 + ln16;
    float4 st;
    st.x = ca[0] + cb[0] + b2v.x;
    st.y = ca[1] + cb[1] + b2v.y;
    st.z = ca[2] + cb[2] + b2v.z;
    st.w = ca[3] + cb[3] + b2v.w;
    *(float4*)&x3b[l_loc*36 + jh*16 + quad*4] = st;
  }
  __syncthreads();

  // -------- phase C: sigmoid/affine/out + logdet --------
  float ld = 0.f;
  #pragma unroll
  for (int i = 0; i < 2; i++) {
    int idx = tid + i*1024;          // (q 0..15, l_loc 0..127)
    int l_loc = idx & 127, q = idx >> 7;
    int lo = lb + l_loc;
    if (l_loc < 126 && lo < 2048) {
      float sv = 1.f / (1.f + __expf(-(x3b[l_loc*36 + q] + 2.f))) + 1e-7f;
      float mv = x3b[l_loc*36 + q + 16];
      int gi = s*(NSQ*Lc) + (16 + q)*Lc + lo;
      out[gi] = sv * (h[gi] + mv);
      ld += __logf(sv);
    }
  }
  #pragma unroll
  for (int off = 32; off > 0; off >>= 1) ld += __shfl_down(ld, off);
  if ((tid & 63) == 0) red[w] = ld;
  __syncthreads();
  if (tid == 0) {
    float tot = 0.f;
    #pragma unroll
    for (int i = 0; i < 16; i++) tot += red[i];
    atomicAdd(&out[OUT_H + s], tot);
  }
}

// ---------------------------------------------------------------------------
extern "C" void kernel_launch(void* const* d_in, const int* in_sizes, int n_in,
                              void* d_out, int out_size, void* d_ws, size_t ws_size,
                              hipStream_t stream) {
  const float* h   = (const float*)d_in[0];
  const float* emb = (const float*)d_in[1];
  const float* Wa  = (const float*)d_in[2];
  const float* ba  = (const float*)d_in[3];
  const float* Wb  = (const float*)d_in[4];
  const float* bb  = (const float*)d_in[5];
  const float* W1  = (const float*)d_in[6];
  const float* b1  = (const float*)d_in[7];
  const float* W2  = (const float*)d_in[8];
  const float* b2  = (const float*)d_in[9];
  float* out = (float*)d_out;
  char* ws = (char*)d_ws;

  float* dynW = (float*)(ws + 0);                          // 384 KiB
  float* dynB = (float*)(ws + 393216);                     // 128 KiB
  unsigned short* W1bf = (unsigned short*)(ws + 524288);   // 512 KiB
  unsigned short* W2bf = (unsigned short*)(ws + 1048576);  // 96 KiB
  if (ws_size < 1179648ull) return;                        // ~1.2 MB needed

  const int smem_bytes = 153728;  // max(stage 92160, x2t 135200 + x3b 18432 + red)
  static int attr_set = 0;
  (void)hipFuncSetAttribute((const void*)k_fused,
                            hipFuncAttributeMaxDynamicSharedMemorySize,
                            smem_bytes);
  (void)attr_set;

  k_prep<<<512, 256, 0, stream>>>(h, emb, Wa, ba, Wb, bb, W1, W2,
                                  dynW, dynB, W1bf, W2bf, out);
  k_fused<<<dim3(17, 64), 1024, smem_bytes, stream>>>(h, W1bf, b1, W2bf, b2,
                                                      dynW, dynB, out);
}

// Round 4
// 325.314 us; speedup vs baseline: 1.3545x; 1.3545x over previous
//
#include <hip/hip_runtime.h>
#include <stdint.h>

#define S 64
#define NSQ 32
#define Lc 2048
#define Cc 512
#define Ec 128
#define OUT_H (S*NSQ*Lc)   /* 4194304 */

typedef __bf16 bf16x8 __attribute__((ext_vector_type(8)));
typedef float floatx4 __attribute__((ext_vector_type(4)));

__device__ __forceinline__ unsigned short f2bf(float f){
  union { float f; uint32_t u; } v; v.f = f;
  uint32_t r = v.u + 0x7fffu + ((v.u >> 16) & 1u);
  return (unsigned short)(r >> 16);
}

// ---------------------------------------------------------------------------
// k_prep: dynamic weights w[s][c][k], b[s][c]; W1->bf16; W2 rearrange->bf16;
// zero logdet.   grid 512 x 256   (~2 MB traffic, few us)
// ---------------------------------------------------------------------------
__global__ void k_prep(const float* __restrict__ emb,
                       const float* __restrict__ Wa, const float* __restrict__ ba,
                       const float* __restrict__ Wb, const float* __restrict__ bb,
                       const float* __restrict__ W1, const float* __restrict__ W2,
                       float* __restrict__ dynW, float* __restrict__ dynB,
                       unsigned short* __restrict__ W1bf, unsigned short* __restrict__ W2bf,
                       float* __restrict__ out)
{
  __shared__ float embl[Ec];
  int tid = threadIdx.x;
  int b = blockIdx.x;          // 512 blocks, 8 per sample
  int s = b >> 3;
  int o = ((b & 7) << 8) | tid;   // 0..2047 (1536 dynW dots + 512 dynB dots)
  if (tid < Ec) embl[tid] = emb[s*Ec + tid];
  __syncthreads();
  const float* row; float bias; float* dst;
  if (o < 1536) { row = Wa + o*Ec; bias = ba[o]; dst = dynW + s*1536 + o; }
  else { int c = o - 1536; row = Wb + c*Ec; bias = bb[c]; dst = dynB + s*Cc + c; }
  float acc = bias;
  const float4* r4 = (const float4*)row;
  #pragma unroll 8
  for (int e = 0; e < Ec/4; e++) {
    float4 rv = r4[e];
    acc += embl[4*e]*rv.x + embl[4*e+1]*rv.y + embl[4*e+2]*rv.z + embl[4*e+3]*rv.w;
  }
  *dst = acc;

  int gtid = b*256 + tid;      // 0..131071
  // W1 convert: 262144 elems, 2/thread. W1 is [o][c][1] row-major == [o][c].
  {
    float2 wv = ((const float2*)W1)[gtid];
    W1bf[2*gtid]   = f2bf(wv.x);
    W1bf[2*gtid+1] = f2bf(wv.y);
  }
  // W2 rearrange: dst [k][j][c] <- src [j][c][k]  (49152 elems)
  if (gtid < 3*32*Cc) {
    int k = gtid >> 14;
    int rem = gtid & 16383;
    int j = rem >> 9, c = rem & 511;
    W2bf[gtid] = f2bf(W2[j*1536 + c*3 + k]);
  }
  if (gtid < S) out[OUT_H + gtid] = 0.f;   // logdet accumulators
}

// ---------------------------------------------------------------------------
// k_fused: per (l-tile, sample) block:
//   phase A: X2[512 o][128 ll] = relu(W1 @ x + b1), x computed on the fly
//            from h + dynamic depthwise weights; x2 -> LDS bf16 [130][532]
//   phase B: x3[32 j][128 l] = KW-3 conv(W2, x2) + b2 (MFMA, x2 from LDS)
//   phase C: h1 copy + s=sigmoid+eps, m; h2' = s*(h2+m); logdet reduce.
// block 1024 thr (16 waves, 1 block/CU); grid (17 tiles, 64 samples);
// lb = t*126; x2 cols l_glob = lb-1+ll; valid conv outputs l_loc in [0,126).
// ---------------------------------------------------------------------------
__global__ void __launch_bounds__(1024, 4) k_fused(
    const float* __restrict__ h,
    const unsigned short* __restrict__ W1bf, const float* __restrict__ b1,
    const unsigned short* __restrict__ W2bf, const float* __restrict__ b2,
    const float* __restrict__ dynW, const float* __restrict__ dynB,
    float* __restrict__ out)
{
  extern __shared__ char smem[];
  unsigned short* As  = (unsigned short*)smem;            // [512][72] (phase A)
  unsigned short* Bs  = (unsigned short*)(smem + 73728);  // [128][72] (phase A)
  unsigned short* x2t = (unsigned short*)smem;            // [130][532] (phase B)
  float* x3b = (float*)(smem + 138320);                   // [128][36]
  float* red = (float*)(smem + 156752);                   // [16]

  int tid = threadIdx.x;
  int t = blockIdx.x, s = blockIdx.y;
  int lb = t*126;
  int w = tid >> 6, ln16 = tid & 15, quad = (tid & 63) >> 4;
  int wm = w >> 1, wn = w & 1;          // GEMM wave grid: 8 (o) x 2 (ll)
  int cl = tid & 63, lg = tid >> 6;     // x staging: c-lane, ll-group
  int ll0 = lg*8;

  const float* hbase = h + s*(NSQ*Lc);
  const float* dwp = dynW + s*1536;
  const float* dbp = dynB + s*Cc;

  floatx4 acc[4][4];
  #pragma unroll
  for (int mi = 0; mi < 4; mi++)
    #pragma unroll
    for (int ni = 0; ni < 4; ni++)
      acc[mi][ni] = (floatx4){0.f,0.f,0.f,0.f};

  // -------- phase A: 8 K-chunks of 64 channels --------
  for (int ch = 0; ch < 8; ch++) {
    int c0 = ch*64;
    __syncthreads();   // previous chunk's frag reads done; LDS reusable
    // stage A tile: W1 rows (512 x 64 bf16)
    #pragma unroll
    for (int j = 0; j < 4; j++) {
      int u = tid + j*1024;
      int row = u >> 3, c16 = u & 7;
      *(uint4*)&As[row*72 + c16*8] = *(const uint4*)&W1bf[row*512 + c0 + c16*8];
    }
    // stage B tile: x(c, ll) computed on the fly (64 c x 128 ll)
    {
      int c_ = c0 + cl, q_ = c_ >> 5;
      const float* hr = hbase + q_*Lc;
      float w0c = dwp[c_*3], w1c = dwp[c_*3+1], w2c = dwp[c_*3+2];
      float bxc = dbp[c_];
      float ph[10];
      int base_ = lb - 2 + ll0;
      #pragma unroll
      for (int m = 0; m < 10; m++) {
        int hi_ = base_ + m;
        ph[m] = ((unsigned)hi_ < 2048u) ? hr[hi_] : 0.f;
      }
      #pragma unroll
      for (int i = 0; i < 8; i++) {
        float v = fmaxf(w0c*ph[i] + w1c*ph[i+1] + w2c*ph[i+2] + bxc, 0.f);
        Bs[(ll0 + i)*72 + cl] = f2bf(v);
      }
    }
    __syncthreads();
    #pragma unroll
    for (int kk = 0; kk < 64; kk += 32) {
      bf16x8 af[4], bfr[4];
      #pragma unroll
      for (int mi = 0; mi < 4; mi++)
        af[mi] = *(const bf16x8*)&As[(wm*64 + mi*16 + ln16)*72 + kk + quad*8];
      #pragma unroll
      for (int ni = 0; ni < 4; ni++)
        bfr[ni] = *(const bf16x8*)&Bs[(wn*64 + ni*16 + ln16)*72 + kk + quad*8];
      #pragma unroll
      for (int mi = 0; mi < 4; mi++)
        #pragma unroll
        for (int ni = 0; ni < 4; ni++)
          acc[mi][ni] = __builtin_amdgcn_mfma_f32_16x16x32_bf16(af[mi], bfr[ni], acc[mi][ni], 0, 0, 0);
    }
  }
  __syncthreads();   // all frag reads done before x2t overwrites As/Bs

  // -------- epilogue A: relu+b1 -> x2t (bf16), zero-pad invalid l --------
  #pragma unroll
  for (int mi = 0; mi < 4; mi++) {
    int o = wm*64 + mi*16 + quad*4;
    float4 b1v = *(const float4*)(b1 + o);
    #pragma unroll
    for (int ni = 0; ni < 4; ni++) {
      int ll = wn*64 + ni*16 + ln16;
      int lglob = lb - 1 + ll;
      ushort4 st;
      if ((unsigned)lglob < 2048u) {
        st.x = f2bf(fmaxf(acc[mi][ni][0] + b1v.x, 0.f));
        st.y = f2bf(fmaxf(acc[mi][ni][1] + b1v.y, 0.f));
        st.z = f2bf(fmaxf(acc[mi][ni][2] + b1v.z, 0.f));
        st.w = f2bf(fmaxf(acc[mi][ni][3] + b1v.w, 0.f));
      } else {
        st.x = 0; st.y = 0; st.z = 0; st.w = 0;   // conv2 zero-pad columns
      }
      *(ushort4*)&x2t[ll*532 + o] = st;
    }
  }
  if (tid < 532) ((uint32_t*)&x2t[128*532])[tid] = 0;  // rows 128,129 = 0
  __syncthreads();

  // -------- phase B: KW=3 conv via MFMA; wave = (jh, nt) --------
  {
    int jh = w & 1, nt = w >> 1;
    floatx4 ca = (floatx4){0.f,0.f,0.f,0.f};
    floatx4 cb = (floatx4){0.f,0.f,0.f,0.f};
    #pragma unroll
    for (int k = 0; k < 3; k++) {
      const unsigned short* Wk = W2bf + k*16384 + (jh*16 + ln16)*512;
      const unsigned short* xr = x2t + (nt*16 + ln16 + k)*532;
      #pragma unroll
      for (int c0 = 0; c0 < 512; c0 += 64) {
        bf16x8 a0 = *(const bf16x8*)&Wk[c0 + quad*8];
        bf16x8 v0 = *(const bf16x8*)&xr[c0 + quad*8];
        ca = __builtin_amdgcn_mfma_f32_16x16x32_bf16(a0, v0, ca, 0, 0, 0);
        bf16x8 a1 = *(const bf16x8*)&Wk[c0 + 32 + quad*8];
        bf16x8 v1 = *(const bf16x8*)&xr[c0 + 32 + quad*8];
        cb = __builtin_amdgcn_mfma_f32_16x16x32_bf16(a1, v1, cb, 0, 0, 0);
      }
    }
    float4 b2v = *(const float4*)(b2 + jh*16 + quad*4);
    int l_loc = nt*16 + ln16;
    float4 st;
    st.x = ca[0] + cb[0] + b2v.x;
    st.y = ca[1] + cb[1] + b2v.y;
    st.z = ca[2] + cb[2] + b2v.z;
    st.w = ca[3] + cb[3] + b2v.w;
    *(float4*)&x3b[l_loc*36 + jh*16 + quad*4] = st;
  }
  __syncthreads();

  // -------- phase C: h1 copy + sigmoid/affine/out + logdet --------
  float ld = 0.f;
  #pragma unroll
  for (int i = 0; i < 4; i++) {
    int idx = tid + i*1024;          // 4096 = (q 0..31) x (l_loc 0..127)
    int l_loc = idx & 127, q = idx >> 7;
    int lo = lb + l_loc;
    if (l_loc < 126 && lo < 2048) {
      int gi = s*(NSQ*Lc) + q*Lc + lo;
      if (q < 16) {
        out[gi] = h[gi];             // h1 passthrough
      } else {
        float sv = 1.f / (1.f + __expf(-(x3b[l_loc*36 + (q-16)] + 2.f))) + 1e-7f;
        float mv = x3b[l_loc*36 + (q-16) + 16];
        out[gi] = sv * (h[gi] + mv);
        ld += __logf(sv);
      }
    }
  }
  #pragma unroll
  for (int off = 32; off > 0; off >>= 1) ld += __shfl_down(ld, off);
  if ((tid & 63) == 0) red[w] = ld;
  __syncthreads();
  if (tid == 0) {
    float tot = 0.f;
    #pragma unroll
    for (int i = 0; i < 16; i++) tot += red[i];
    atomicAdd(&out[OUT_H + s], tot);
  }
}

// ---------------------------------------------------------------------------
extern "C" void kernel_launch(void* const* d_in, const int* in_sizes, int n_in,
                              void* d_out, int out_size, void* d_ws, size_t ws_size,
                              hipStream_t stream) {
  const float* h   = (const float*)d_in[0];
  const float* emb = (const float*)d_in[1];
  const float* Wa  = (const float*)d_in[2];
  const float* ba  = (const float*)d_in[3];
  const float* Wb  = (const float*)d_in[4];
  const float* bb  = (const float*)d_in[5];
  const float* W1  = (const float*)d_in[6];
  const float* b1  = (const float*)d_in[7];
  const float* W2  = (const float*)d_in[8];
  const float* b2  = (const float*)d_in[9];
  float* out = (float*)d_out;
  char* ws = (char*)d_ws;

  float* dynW = (float*)(ws + 0);                          // 384 KiB
  float* dynB = (float*)(ws + 393216);                     // 128 KiB
  unsigned short* W1bf = (unsigned short*)(ws + 524288);   // 512 KiB
  unsigned short* W2bf = (unsigned short*)(ws + 1048576);  // 96 KiB
  if (ws_size < 1179648ull) return;                        // ~1.2 MB needed

  const int smem_bytes = 156816;  // max(stage 92160, x2t 138320 + x3b 18432 + red 64)
  (void)hipFuncSetAttribute((const void*)k_fused,
                            hipFuncAttributeMaxDynamicSharedMemorySize,
                            smem_bytes);

  k_prep<<<512, 256, 0, stream>>>(emb, Wa, ba, Wb, bb, W1, W2,
                                  dynW, dynB, W1bf, W2bf, out);
  k_fused<<<dim3(17, 64), 1024, smem_bytes, stream>>>(h, W1bf, b1, W2bf, b2,
                                                      dynW, dynB, out);
}